// Round 11
// baseline (41.915 us; speedup 1.0000x reference)
//
#include <hip/hip_runtime.h>
#include <hip/hip_bf16.h>
#include <math.h>

// inputs: [B=64, I=2048, P=16] f32
// W:      [I=2048, J=32, P=16, D=32] f32
// bias:   [1, I, J, 1, 1] f32
// out:    [B=64, J=32, D=32] f32
#define I_CAP 2048
#define P_DIM 16
#define J_CAP 32
#define D_DIM 32
#define B_SZ  64
#define KCN   32            // i-chunks; partial = KCN*32*2048 f32 = 8 MB
#define IPB   (I_CAP / KCN) // 64 i per block
#define NWAVE 8
#define IPW   (IPB / NWAVE) // 8 i per wave

typedef __attribute__((ext_vector_type(8)))  short short8_t;
typedef __attribute__((ext_vector_type(16))) float f32x16;

__device__ __forceinline__ short f2bf(float f) {
    __hip_bfloat16 h = __float2bfloat16(f);   // RNE
    return __builtin_bit_cast(short, h);
}

// ---------------- k0: A-prep into bf16 MFMA-fragment order (CONSUMER FORM) ---
// Thread = (i, lane l). For mf in {0,1}, e in {0..7}:
//   AstageS[i*1024 + mf*512 + l*8 + e] = bf16(inputs[((l&31)+32*mf)*32768 + i*16 + (l>>5)*8 + e])
// Literally the main kernel's A-frag formulas -> correct by construction.
// One-time gather (~2-3us); stores coalesced 1KB/wave-instr. 4 MB total.
__global__ __launch_bounds__(256) void caps_aprep_k(const float* __restrict__ inputs,
                                                    short* __restrict__ AstageS) {
    const int tid = blockIdx.x * 256 + threadIdx.x;   // 0..131071
    const int l = tid & 63;
    const int i = tid >> 6;                            // 0..2047 (wave-uniform)
#pragma unroll
    for (int mf = 0; mf < 2; ++mf) {
        const float* src = inputs + (size_t)((l & 31) + 32 * mf) * 32768
                                  + (size_t)i * 16 + (l >> 5) * 8;
        float4 v0 = *(const float4*)src;
        float4 v1 = *(const float4*)(src + 4);
        short8_t s;
        s[0] = f2bf(v0.x); s[1] = f2bf(v0.y); s[2] = f2bf(v0.z); s[3] = f2bf(v0.w);
        s[4] = f2bf(v1.x); s[5] = f2bf(v1.y); s[6] = f2bf(v1.z); s[7] = f2bf(v1.w);
        *(short8_t*)(AstageS + (size_t)i * 1024 + mf * 512 + l * 8) = s;
    }
}

// ---------------- k1: fused softmax + main GEMM via bf16 MFMA ----------------
// R7-PROVEN structure (register W loads, compiler-managed waits, no manual
// vmcnt, no DMA -- the R8/R9/R10 manual-vmcnt path was nondeterministic).
// Block (kc, jq) = 512 thr = 8 waves on disjoint 8-i subranges; every wave
// computes j0..j0+3 for all 64 b; per-(wave,i) W read = 8 KB contiguous.
// grid = 32 kc x 8 jq = 256 = 1 block/CU. XCD-chunked swizzle.
// NEW: A-frags come pre-converted (bf16) from AstageS in fragment order ->
// 2 coalesced 16B short8 loads per round (vs 4 x 64-line f32 gathers) and
// zero A-side f2bf in the hot loop.
// B-frag: lane l -> n=d=(l&31), k=p=(l>>5)*8+e   (k-permutation-safe: A uses same map)
// A-frag: lane l -> m=b=(l&31)+32*mf, k=p=(l>>5)*8+e  == AstageS[i][mf][l][0..8)
// C/D:    b = mf*32 + (reg&3) + 8*(reg>>2) + 4*(l>>5), d = l&31   [m74/m101]
__global__ __launch_bounds__(512, 2) void caps_main_k(const short* __restrict__ AstageS,
                                                      const float* __restrict__ W,
                                                      const float* __restrict__ bias,
                                                      float* __restrict__ partial) {
    __shared__ float red[NWAVE * 2048];   // 64 KB
    __shared__ float c_lds[IPB][4];       // c[i_local][j0..j0+3]
    const int t  = threadIdx.x;
    const int l  = t & 63;
    const int wv = t >> 6;                // 0..7

    // chunked XCD swizzle (bijective: 256 % 8 == 0)
    const int orig = blockIdx.x;
    const int wgid = (orig & 7) * 32 + (orig >> 3);
    const int kc = wgid >> 3;             // 0..31
    const int jq = wgid & 7;              // 0..7
    const int j0 = jq * 4;

    const int g  = l >> 5;     // p-half selector (k-group)
    const int dn = l & 31;     // d for B-frag

    const int i0blk = kc * IPB;
    const int i0    = i0blk + wv * IPW;

    // ---- fused softmax: c[i, j0..j0+3] for this block's 64 i's ----
    {
        const int jj = t & 31;            // j
        const int ib = t >> 5;            // 0..15
        const int jr = jj - j0;
#pragma unroll
        for (int pass = 0; pass < 4; ++pass) {
            const int ii = pass * 16 + ib;
            float x = bias[(i0blk + ii) * J_CAP + jj];
            float m = x;
#pragma unroll
            for (int k = 16; k >= 1; k >>= 1) m = fmaxf(m, __shfl_xor(m, k));
            float e = expf(x - m);
            float s = e;
#pragma unroll
            for (int k = 16; k >= 1; k >>= 1) s += __shfl_xor(s, k);
            if ((unsigned)jr < 4u) c_lds[ii][jr] = e / s;
        }
    }
    __syncthreads();

    const float* wlane = W + (((size_t)(i0 * J_CAP + j0)) << 9) + g * 256 + dn;
    const short* asrcS = AstageS + (size_t)i0 * 1024 + l * 8;   // bf16 frag-order A

    f32x16 acc[4][2];   // [jj][b-half]
#pragma unroll
    for (int jj = 0; jj < 4; ++jj) { acc[jj][0] = (f32x16){}; acc[jj][1] = (f32x16){}; }

#pragma unroll 2
    for (int r = 0; r < IPW; ++r) {
        // W: 8 KB contiguous per (wave, i): j0..j0+3, each 2 KB
        float wb[4][8];
#pragma unroll
        for (int jj = 0; jj < 4; ++jj)
#pragma unroll
            for (int e = 0; e < 8; ++e)
                wb[jj][e] = wlane[(size_t)r * 16384 + jj * 512 + e * 32];

        // A: 2 coalesced short8 loads (bf16 fragments, pre-converted)
        short8_t af0 = *(const short8_t*)(asrcS + (size_t)r * 1024);        // mf=0
        short8_t af1 = *(const short8_t*)(asrcS + (size_t)r * 1024 + 512);  // mf=1

#pragma unroll
        for (int jj = 0; jj < 4; ++jj) {
            const float cj = c_lds[wv * IPW + r][jj];
            short8_t bf;
#pragma unroll
            for (int e = 0; e < 8; ++e) bf[e] = f2bf(wb[jj][e] * cj);
            acc[jj][0] = __builtin_amdgcn_mfma_f32_32x32x16_bf16(af0, bf, acc[jj][0], 0, 0, 0);
            acc[jj][1] = __builtin_amdgcn_mfma_f32_32x32x16_bf16(af1, bf, acc[jj][1], 0, 0, 0);
        }
    }

    // ---- epilogue: 4 passes (one per jj): 8-wave LDS reduce -> partial ----
#pragma unroll
    for (int jj = 0; jj < 4; ++jj) {
        __syncthreads();   // pass p-1 reads done / softmax reads done
        {
            float* rw = red + wv * 2048;
#pragma unroll
            for (int reg = 0; reg < 16; ++reg) {
                const int b0 = (reg & 3) + 8 * (reg >> 2) + 4 * g;
                rw[b0 * 32 + dn]        = acc[jj][0][reg];
                rw[(b0 + 32) * 32 + dn] = acc[jj][1][reg];
            }
        }
        __syncthreads();
        {
            const int o = t * 4;   // 512 thr x 4 floats = 2048
            float4 v = {0.f, 0.f, 0.f, 0.f};
#pragma unroll
            for (int w8 = 0; w8 < NWAVE; ++w8) {
                float4 p = *(const float4*)(red + w8 * 2048 + o);
                v.x += p.x; v.y += p.y; v.z += p.z; v.w += p.w;
            }
            *(float4*)(partial + (size_t)(kc * J_CAP + j0 + jj) * 2048 + o) = v;
        }
    }
}

// ---------------- k2: reduce KCN partials + squash (vectorized) ----------------
__global__ __launch_bounds__(256) void caps_reduce_squash_k(const float* __restrict__ partial,
                                                            float* __restrict__ out) {
    const int tid2 = blockIdx.x * 256 + threadIdx.x;
    const int row  = tid2 >> 4;
    const int sub  = tid2 & 15;
    const int d4   = sub >> 1;
    const int half = sub & 1;
    const int j = row >> 6, b = row & 63;

    const float* src = partial + ((size_t)(half * 16) * J_CAP + j) * 2048 + b * 32 + d4 * 4;
    float4 v = {0.f, 0.f, 0.f, 0.f};
#pragma unroll
    for (int kc = 0; kc < 16; ++kc) {
        float4 p = *(const float4*)(src + (size_t)kc * J_CAP * 2048);
        v.x += p.x; v.y += p.y; v.z += p.z; v.w += p.w;
    }
    // combine the two kc-halves (lane pair differs only in `half`)
    v.x += __shfl_xor(v.x, 1); v.y += __shfl_xor(v.y, 1);
    v.z += __shfl_xor(v.z, 1); v.w += __shfl_xor(v.w, 1);

    float sq = v.x * v.x + v.y * v.y + v.z * v.z + v.w * v.w;
#pragma unroll
    for (int m = 2; m <= 8; m <<= 1) sq += __shfl_xor(sq, m);
    // scale = s2 / (1+s2) / sqrt(s2)  (exactly as reference)
    float scale = sq / (1.0f + sq) / sqrtf(sq);
    if (half == 0) {
        float4 o = {v.x * scale, v.y * scale, v.z * scale, v.w * scale};
        *(float4*)(out + (size_t)b * (J_CAP * D_DIM) + j * D_DIM + d4 * 4) = o;
    }
}

extern "C" void kernel_launch(void* const* d_in, const int* in_sizes, int n_in,
                              void* d_out, int out_size, void* d_ws, size_t ws_size,
                              hipStream_t stream) {
    const float* inputs = (const float*)d_in[0];
    const float* W      = (const float*)d_in[1];
    const float* bias   = (const float*)d_in[2];
    float* out = (float*)d_out;

    short* AstageS = (short*)d_ws;                            // 4 MB (bf16 frag-order A)
    float* partial = (float*)(AstageS + (size_t)I_CAP * 1024); // 8 MB

    caps_aprep_k<<<dim3(512), dim3(256), 0, stream>>>(inputs, AstageS);
    caps_main_k<<<dim3(KCN * 8), dim3(512), 0, stream>>>(AstageS, W, bias, partial);
    caps_reduce_squash_k<<<dim3(128), dim3(256), 0, stream>>>(partial, out);
}

// Round 12
// 36.264 us; speedup vs baseline: 1.1558x; 1.1558x over previous
//
#include <hip/hip_runtime.h>
#include <hip/hip_bf16.h>
#include <math.h>

// inputs: [B=64, I=2048, P=16] f32
// W:      [I=2048, J=32, P=16, D=32] f32
// bias:   [1, I, J, 1, 1] f32
// out:    [B=64, J=32, D=32] f32
#define I_CAP 2048
#define P_DIM 16
#define J_CAP 32
#define D_DIM 32
#define B_SZ  64
#define KCN   32            // i-chunks; partial = KCN*32*2048 f32 = 8 MB
#define IPB   (I_CAP / KCN) // 64 i per block
#define NWAVE 8
#define IPW   (IPB / NWAVE) // 8 i per wave

typedef __attribute__((ext_vector_type(8)))  short short8_t;
typedef __attribute__((ext_vector_type(16))) float f32x16;

__device__ __forceinline__ short f2bf(float f) {
    __hip_bfloat16 h = __float2bfloat16(f);   // RNE
    return __builtin_bit_cast(short, h);
}

// ---------------- k1: fused softmax + main GEMM via bf16 MFMA ----------------
// R12: b-split for occupancy. Block (kc, jq, bh): 512 thr = 8 waves on
// disjoint 8-i subranges; every wave computes j0..j0+3 for the 32 b's of its
// bh half -> acc = 4 x f32x16 = 64 VGPR -> launch_bounds(512,4) = 4 waves/SIMD
// = 16 waves/CU, 2 blocks/CU (LDS 33KB). Per-(wave,i) W chunk still 8 KB
// contiguous; the bh-partner block re-reads it from XCD L2 (pairs are adjacent
// in dispatch order and co-XCD by the chunked swizzle).
// grid = 32 kc x 8 jq x 2 bh = 512 (bijective: 512 % 8 == 0).
// B-frag: lane l -> n=d=(l&31), k=p=(l>>5)*8+e   (k-permutation-safe: A uses same map)
// A-frag: lane l -> m-row=(l&31) -> b = bh*32+(l&31), k=p=(l>>5)*8+e
// C/D:    brow = (reg&3) + 8*(reg>>2) + 4*(l>>5), d = l&31   [m74/m101]
__global__ __launch_bounds__(512, 4) void caps_main_k(const float* __restrict__ inputs,
                                                      const float* __restrict__ W,
                                                      const float* __restrict__ bias,
                                                      float* __restrict__ partial) {
    __shared__ float red[NWAVE * 1024];   // 32 KB: [wave][32 b][32 d]
    __shared__ float c_lds[IPB][4];       // c[i_local][j0..j0+3]
    const int t  = threadIdx.x;
    const int l  = t & 63;
    const int wv = t >> 6;                // 0..7

    // chunked XCD swizzle (bijective: 512 % 8 == 0); xcd owns 4kc x 8jq x 2bh
    const int orig = blockIdx.x;
    const int wgid = (orig & 7) * 64 + (orig >> 3);
    const int kc = wgid >> 4;             // 0..31
    const int jq = (wgid >> 1) & 7;       // 0..7
    const int bh = wgid & 1;              // 0..1  (b-half; pair adjacent -> co-XCD)
    const int j0 = jq * 4;

    const int g  = l >> 5;     // p-half selector (k-group)
    const int dn = l & 31;     // d for B-frag / m-row for A-frag

    const int i0blk = kc * IPB;
    const int i0    = i0blk + wv * IPW;

    // ---- fused softmax: c[i, j0..j0+3] for this block's 64 i's ----
    {
        const int jj = t & 31;            // j
        const int ib = t >> 5;            // 0..15
        const int jr = jj - j0;
#pragma unroll
        for (int pass = 0; pass < 4; ++pass) {
            const int ii = pass * 16 + ib;
            float x = bias[(i0blk + ii) * J_CAP + jj];
            float m = x;
#pragma unroll
            for (int k = 16; k >= 1; k >>= 1) m = fmaxf(m, __shfl_xor(m, k));
            float e = expf(x - m);
            float s = e;
#pragma unroll
            for (int k = 16; k >= 1; k >>= 1) s += __shfl_xor(s, k);
            if ((unsigned)jr < 4u) c_lds[ii][jr] = e / s;
        }
    }
    __syncthreads();

    const float* wlane = W + (((size_t)(i0 * J_CAP + j0)) << 9) + g * 256 + dn;
    const float* asrc  = inputs + (size_t)(bh * 32 + dn) * 32768 + (size_t)i0 * 16 + g * 8;

    f32x16 acc[4];   // [jj] for this b-half
#pragma unroll
    for (int jj = 0; jj < 4; ++jj) acc[jj] = (f32x16){};

#pragma unroll 2
    for (int r = 0; r < IPW; ++r) {
        // A: 8 consecutive fp32 of inputs[b, i, :] (gather over 32 b-rows)
        float4 a0 = *(const float4*)(asrc + r * 16);
        float4 a1 = *(const float4*)(asrc + r * 16 + 4);
        short8_t af;
        af[0] = f2bf(a0.x); af[1] = f2bf(a0.y); af[2] = f2bf(a0.z); af[3] = f2bf(a0.w);
        af[4] = f2bf(a1.x); af[5] = f2bf(a1.y); af[6] = f2bf(a1.z); af[7] = f2bf(a1.w);

        // W: 8 KB contiguous per (wave, i), staged as two 4 KB j-pairs
#pragma unroll
        for (int jh = 0; jh < 2; ++jh) {
            float wb[2][8];
#pragma unroll
            for (int q = 0; q < 2; ++q)
#pragma unroll
                for (int e = 0; e < 8; ++e)
                    wb[q][e] = wlane[(size_t)r * 16384 + (jh * 2 + q) * 512 + e * 32];
#pragma unroll
            for (int q = 0; q < 2; ++q) {
                const int jj = jh * 2 + q;
                const float cj = c_lds[wv * IPW + r][jj];
                short8_t bf;
#pragma unroll
                for (int e = 0; e < 8; ++e) bf[e] = f2bf(wb[q][e] * cj);
                acc[jj] = __builtin_amdgcn_mfma_f32_32x32x16_bf16(af, bf, acc[jj], 0, 0, 0);
            }
        }
    }

    // ---- epilogue: 4 passes (one per jj): 8-wave LDS reduce -> partial ----
#pragma unroll
    for (int jj = 0; jj < 4; ++jj) {
        __syncthreads();   // pass jj-1 reads done / softmax reads done
        {
            float* rw = red + wv * 1024;
#pragma unroll
            for (int reg = 0; reg < 16; ++reg) {
                const int b0 = (reg & 3) + 8 * (reg >> 2) + 4 * g;   // 0..31
                rw[b0 * 32 + dn] = acc[jj][reg];                     // 2-way bank (free)
            }
        }
        __syncthreads();
        {
            const int o = t * 2;   // 512 thr x 2 floats = 1024
            float2 v = {0.f, 0.f};
#pragma unroll
            for (int w8 = 0; w8 < NWAVE; ++w8) {
                float2 p = *(const float2*)(red + w8 * 1024 + o);
                v.x += p.x; v.y += p.y;
            }
            // partial[(kc*32 + j0+jj)*2048 + bh*1024 + o]
            *(float2*)(partial + (size_t)(kc * J_CAP + j0 + jj) * 2048 + bh * 1024 + o) = v;
        }
    }
}

// ---------------- k2: reduce KCN partials + squash (vectorized) ----------------
// 128 blocks x 256 thr = 32768 threads. tid2 -> row = tid2>>4 (j = row>>6,
// b = row&63), d4 = (tid2>>1)&7, half = tid2&1 (kc half). Each thread sums 16
// kc's as float4, pair-combines via shfl_xor(1), row-squash via shfl 2/4/8.
__global__ __launch_bounds__(256) void caps_reduce_squash_k(const float* __restrict__ partial,
                                                            float* __restrict__ out) {
    const int tid2 = blockIdx.x * 256 + threadIdx.x;
    const int row  = tid2 >> 4;
    const int sub  = tid2 & 15;
    const int d4   = sub >> 1;
    const int half = sub & 1;
    const int j = row >> 6, b = row & 63;

    const float* src = partial + ((size_t)(half * 16) * J_CAP + j) * 2048 + b * 32 + d4 * 4;
    float4 v = {0.f, 0.f, 0.f, 0.f};
#pragma unroll
    for (int kc = 0; kc < 16; ++kc) {
        float4 p = *(const float4*)(src + (size_t)kc * J_CAP * 2048);
        v.x += p.x; v.y += p.y; v.z += p.z; v.w += p.w;
    }
    // combine the two kc-halves (lane pair differs only in `half`)
    v.x += __shfl_xor(v.x, 1); v.y += __shfl_xor(v.y, 1);
    v.z += __shfl_xor(v.z, 1); v.w += __shfl_xor(v.w, 1);

    float sq = v.x * v.x + v.y * v.y + v.z * v.z + v.w * v.w;
#pragma unroll
    for (int m = 2; m <= 8; m <<= 1) sq += __shfl_xor(sq, m);
    // scale = s2 / (1+s2) / sqrt(s2)  (exactly as reference)
    float scale = sq / (1.0f + sq) / sqrtf(sq);
    if (half == 0) {
        float4 o = {v.x * scale, v.y * scale, v.z * scale, v.w * scale};
        *(float4*)(out + (size_t)b * (J_CAP * D_DIM) + j * D_DIM + d4 * 4) = o;
    }
}

extern "C" void kernel_launch(void* const* d_in, const int* in_sizes, int n_in,
                              void* d_out, int out_size, void* d_ws, size_t ws_size,
                              hipStream_t stream) {
    const float* inputs = (const float*)d_in[0];
    const float* W      = (const float*)d_in[1];
    const float* bias   = (const float*)d_in[2];
    float* out = (float*)d_out;

    float* partial = (float*)d_ws;   // 32*32*2048 f32 = 8 MB

    caps_main_k<<<dim3(KCN * 8 * 2), dim3(512), 0, stream>>>(inputs, W, bias, partial);
    caps_reduce_squash_k<<<dim3(128), dim3(256), 0, stream>>>(partial, out);
}

// Round 13
// 35.316 us; speedup vs baseline: 1.1868x; 1.0268x over previous
//
#include <hip/hip_runtime.h>
#include <hip/hip_bf16.h>
#include <math.h>

// inputs: [B=64, I=2048, P=16] f32
// W:      [I=2048, J=32, P=16, D=32] f32
// bias:   [1, I, J, 1, 1] f32
// out:    [B=64, J=32, D=32] f32
//
// FINAL (R13 = R7, proven best at 35.4 us):
//   s[b, j*32+d] = sum_{i,p} inputs[b,i,p] * (c[i,j]*W[i,j,p,d]);  out = squash(s)
// Memory-bound: W = 134 MB read exactly once. Ladder of wins:
//   R3  MFMA port (32x32x16 bf16, c folded into B at convert)   111 -> 53
//   R4  partials instead of atomics, no memset                   (restructure)
//   R5  XCD-chunked swizzle + j-pair (4 KB chunks)               59 -> 39
//   R7  8-wave block, NJ=4 (8 KB contiguous chunks/wave-round)   39 -> 35.4
// Nulls (latency/concurrency axis exhausted): R8 manual-vmcnt DMA pipeline
// (also RACED -> abandoned), R11 A-coalescing via prep kernel, R12 b-split
// 16 waves/CU. Main kernel ~28 us = ~5 TB/s sustained W-stream (~80% of the
// 6.3 TB/s copy-ubench ceiling); reduce ~2.5 us; launch/softmax ~4 us.
#define I_CAP 2048
#define P_DIM 16
#define J_CAP 32
#define D_DIM 32
#define B_SZ  64
#define KCN   32            // i-chunks; partial = KCN*32*2048 f32 = 8 MB
#define IPB   (I_CAP / KCN) // 64 i per block
#define NWAVE 8
#define IPW   (IPB / NWAVE) // 8 i per wave

typedef __attribute__((ext_vector_type(8)))  short short8_t;
typedef __attribute__((ext_vector_type(16))) float f32x16;

__device__ __forceinline__ short f2bf(float f) {
    __hip_bfloat16 h = __float2bfloat16(f);   // RNE
    return __builtin_bit_cast(short, h);
}

// ---------------- k1: fused softmax + main GEMM via bf16 MFMA ----------------
// Block (kc, jq): 512 thr = 8 waves on disjoint 8-i subranges; every wave
// computes j0..j0+3 for all 64 b; per-(wave,i) W read = 8 KB CONTIGUOUS.
// grid = 32 kc x 8 jq = 256 = 1 block/CU. Register W loads, compiler-managed
// waits (manual-vmcnt DMA variant raced -- do not reintroduce).
// XCD-chunked bid swizzle: xcd owns 32 blocks = 4 kc x 8 jq -> all 8 sharers
// of each A-slice co-XCD; W region per XCD = 16 MB contiguous.
// B-frag: lane l -> n=d=(l&31), k=p=(l>>5)*8+e   (k-permutation-safe: A uses same map)
// A-frag: lane l -> m=b=(l&31)+32*mf, k=p=(l>>5)*8+e  -> 8 consecutive fp32
// C/D:    b = mf*32 + (reg&3) + 8*(reg>>2) + 4*(l>>5), d = l&31   [m74/m101]
__global__ __launch_bounds__(512, 2) void caps_main_k(const float* __restrict__ inputs,
                                                      const float* __restrict__ W,
                                                      const float* __restrict__ bias,
                                                      float* __restrict__ partial) {
    __shared__ float red[NWAVE * 2048];   // 64 KB
    __shared__ float c_lds[IPB][4];       // c[i_local][j0..j0+3]
    const int t  = threadIdx.x;
    const int l  = t & 63;
    const int wv = t >> 6;                // 0..7

    // chunked XCD swizzle (bijective: 256 % 8 == 0)
    const int orig = blockIdx.x;
    const int wgid = (orig & 7) * 32 + (orig >> 3);
    const int kc = wgid >> 3;             // 0..31
    const int jq = wgid & 7;              // 0..7
    const int j0 = jq * 4;

    const int g  = l >> 5;     // p-half selector (k-group)
    const int dn = l & 31;     // d for B-frag, b for A-frag

    const int i0blk = kc * IPB;
    const int i0    = i0blk + wv * IPW;

    // ---- fused softmax: c[i, j0..j0+3] for this block's 64 i's ----
    {
        const int jj = t & 31;            // j
        const int ib = t >> 5;            // 0..15
        const int jr = jj - j0;
#pragma unroll
        for (int pass = 0; pass < 4; ++pass) {
            const int ii = pass * 16 + ib;
            float x = bias[(i0blk + ii) * J_CAP + jj];
            float m = x;
#pragma unroll
            for (int k = 16; k >= 1; k >>= 1) m = fmaxf(m, __shfl_xor(m, k));
            float e = expf(x - m);
            float s = e;
#pragma unroll
            for (int k = 16; k >= 1; k >>= 1) s += __shfl_xor(s, k);
            if ((unsigned)jr < 4u) c_lds[ii][jr] = e / s;
        }
    }
    __syncthreads();

    const float* wlane  = W + (((size_t)(i0 * J_CAP + j0)) << 9) + g * 256 + dn;
    const float* alane0 = inputs + ((size_t)dn << 15) + (size_t)i0 * 16 + g * 8;
    const float* alane1 = alane0 + ((size_t)32 << 15);

    f32x16 acc[4][2];   // [jj][b-half]
#pragma unroll
    for (int jj = 0; jj < 4; ++jj) { acc[jj][0] = (f32x16){}; acc[jj][1] = (f32x16){}; }

#pragma unroll 2
    for (int r = 0; r < IPW; ++r) {
        // W: 8 KB contiguous per (wave, i): j0..j0+3, each 2 KB
        float wb[4][8];
#pragma unroll
        for (int jj = 0; jj < 4; ++jj)
#pragma unroll
            for (int e = 0; e < 8; ++e)
                wb[jj][e] = wlane[(size_t)r * 16384 + jj * 512 + e * 32];

        float4 a0 = *(const float4*)(alane0 + r * 16);
        float4 a1 = *(const float4*)(alane0 + r * 16 + 4);
        float4 a2 = *(const float4*)(alane1 + r * 16);
        float4 a3 = *(const float4*)(alane1 + r * 16 + 4);

        short8_t af0, af1;
        af0[0] = f2bf(a0.x); af0[1] = f2bf(a0.y); af0[2] = f2bf(a0.z); af0[3] = f2bf(a0.w);
        af0[4] = f2bf(a1.x); af0[5] = f2bf(a1.y); af0[6] = f2bf(a1.z); af0[7] = f2bf(a1.w);
        af1[0] = f2bf(a2.x); af1[1] = f2bf(a2.y); af1[2] = f2bf(a2.z); af1[3] = f2bf(a2.w);
        af1[4] = f2bf(a3.x); af1[5] = f2bf(a3.y); af1[6] = f2bf(a3.z); af1[7] = f2bf(a3.w);

#pragma unroll
        for (int jj = 0; jj < 4; ++jj) {
            const float cj = c_lds[wv * IPW + r][jj];
            short8_t bf;
#pragma unroll
            for (int e = 0; e < 8; ++e) bf[e] = f2bf(wb[jj][e] * cj);
            acc[jj][0] = __builtin_amdgcn_mfma_f32_32x32x16_bf16(af0, bf, acc[jj][0], 0, 0, 0);
            acc[jj][1] = __builtin_amdgcn_mfma_f32_32x32x16_bf16(af1, bf, acc[jj][1], 0, 0, 0);
        }
    }

    // ---- epilogue: 4 passes (one per jj): 8-wave LDS reduce -> partial ----
#pragma unroll
    for (int jj = 0; jj < 4; ++jj) {
        __syncthreads();   // pass jj-1 reads done / softmax reads done
        {
            float* rw = red + wv * 2048;
#pragma unroll
            for (int reg = 0; reg < 16; ++reg) {
                const int b0 = (reg & 3) + 8 * (reg >> 2) + 4 * g;
                rw[b0 * 32 + dn]        = acc[jj][0][reg];
                rw[(b0 + 32) * 32 + dn] = acc[jj][1][reg];
            }
        }
        __syncthreads();
        {
            const int o = t * 4;   // 512 thr x 4 floats = 2048
            float4 v = {0.f, 0.f, 0.f, 0.f};
#pragma unroll
            for (int w8 = 0; w8 < NWAVE; ++w8) {
                float4 p = *(const float4*)(red + w8 * 2048 + o);
                v.x += p.x; v.y += p.y; v.z += p.z; v.w += p.w;
            }
            *(float4*)(partial + (size_t)(kc * J_CAP + j0 + jj) * 2048 + o) = v;
        }
    }
}

// ---------------- k2: reduce KCN partials + squash (vectorized) ----------------
// 128 blocks x 256 thr = 32768 threads. tid2 -> row = tid2>>4 (j = row>>6,
// b = row&63), d4 = (tid2>>1)&7, half = tid2&1 (kc half). Each thread sums 16
// kc's as float4, pair-combines via shfl_xor(1), row-squash via shfl 2/4/8.
__global__ __launch_bounds__(256) void caps_reduce_squash_k(const float* __restrict__ partial,
                                                            float* __restrict__ out) {
    const int tid2 = blockIdx.x * 256 + threadIdx.x;
    const int row  = tid2 >> 4;
    const int sub  = tid2 & 15;
    const int d4   = sub >> 1;
    const int half = sub & 1;
    const int j = row >> 6, b = row & 63;

    const float* src = partial + ((size_t)(half * 16) * J_CAP + j) * 2048 + b * 32 + d4 * 4;
    float4 v = {0.f, 0.f, 0.f, 0.f};
#pragma unroll
    for (int kc = 0; kc < 16; ++kc) {
        float4 p = *(const float4*)(src + (size_t)kc * J_CAP * 2048);
        v.x += p.x; v.y += p.y; v.z += p.z; v.w += p.w;
    }
    // combine the two kc-halves (lane pair differs only in `half`)
    v.x += __shfl_xor(v.x, 1); v.y += __shfl_xor(v.y, 1);
    v.z += __shfl_xor(v.z, 1); v.w += __shfl_xor(v.w, 1);

    float sq = v.x * v.x + v.y * v.y + v.z * v.z + v.w * v.w;
#pragma unroll
    for (int m = 2; m <= 8; m <<= 1) sq += __shfl_xor(sq, m);
    // scale = s2 / (1+s2) / sqrt(s2)  (exactly as reference)
    float scale = sq / (1.0f + sq) / sqrtf(sq);
    if (half == 0) {
        float4 o = {v.x * scale, v.y * scale, v.z * scale, v.w * scale};
        *(float4*)(out + (size_t)b * (J_CAP * D_DIM) + j * D_DIM + d4 * 4) = o;
    }
}

extern "C" void kernel_launch(void* const* d_in, const int* in_sizes, int n_in,
                              void* d_out, int out_size, void* d_ws, size_t ws_size,
                              hipStream_t stream) {
    const float* inputs = (const float*)d_in[0];
    const float* W      = (const float*)d_in[1];
    const float* bias   = (const float*)d_in[2];
    float* out = (float*)d_out;

    float* partial = (float*)d_ws;   // 32*32*2048 f32 = 8 MB

    caps_main_k<<<dim3(KCN * 8), dim3(512), 0, stream>>>(inputs, W, bias, partial);
    caps_reduce_squash_k<<<dim3(128), dim3(256), 0, stream>>>(partial, out);
}